// Round 1
// baseline (504.473 us; speedup 1.0000x reference)
//
#include <hip/hip_runtime.h>
#include <stdint.h>

typedef uint32_t u32;
typedef uint64_t u64;
typedef uint8_t  u8;

#define KEY_MIN   0x3C000000u   /* 0.0078125f; conf = max softmax >= 1/C = 0.01 */
#define SUBSHIFT  10
#define NBUCK     57344         /* (0x3F800000 - 0x3C000000) >> 10 */
#define NBINS     20
#define NB        19            /* NBINS - 1 boundaries */
#define TIECAP    1024

__device__ __forceinline__ u32 bucket_of(u32 key) {
    if (key < KEY_MIN) return 0u;
    u32 b = (key - KEY_MIN) >> SUBSHIFT;
    return b < (u32)NBUCK ? b : (u32)(NBUCK - 1);
}

// ---------------- K1: per-row confidence (max softmax), accuracy, histogram ----
__global__ __launch_bounds__(256) void k1_conf(
        const float* __restrict__ logits, const int* __restrict__ labels,
        u32* __restrict__ keys, u8* __restrict__ accb, u32* __restrict__ hist,
        int N, int C) {
    int i = blockIdx.x * blockDim.x + threadIdx.x;
    if (i >= N) return;
    const float* row = logits + (size_t)i * (size_t)C;
    float m = -3.4e38f, s = 0.f;
    int am = 0;
    if ((C & 3) == 0) {
        const float4* r4 = (const float4*)row;
        int C4 = C >> 2;
        for (int j = 0; j < C4; j++) {
            float4 v = r4[j];
            { float nm = fmaxf(m, v.x); am = (v.x > m) ? (4*j+0) : am; s = s * __expf(m - nm) + __expf(v.x - nm); m = nm; }
            { float nm = fmaxf(m, v.y); am = (v.y > m) ? (4*j+1) : am; s = s * __expf(m - nm) + __expf(v.y - nm); m = nm; }
            { float nm = fmaxf(m, v.z); am = (v.z > m) ? (4*j+2) : am; s = s * __expf(m - nm) + __expf(v.z - nm); m = nm; }
            { float nm = fmaxf(m, v.w); am = (v.w > m) ? (4*j+3) : am; s = s * __expf(m - nm) + __expf(v.w - nm); m = nm; }
        }
    } else {
        for (int c = 0; c < C; c++) {
            float v = row[c];
            float nm = fmaxf(m, v); am = (v > m) ? c : am;
            s = s * __expf(m - nm) + __expf(v - nm); m = nm;
        }
    }
    float conf = 1.0f / s;           // exp(max - lse) == 1/sum(exp(l - max))
    u32 key = __float_as_uint(conf); // monotone for positive floats
    keys[i] = key;
    accb[i] = (labels[i] == am) ? (u8)1 : (u8)0;
    atomicAdd(&hist[bucket_of(key)], 1u);
}

// meta layout (u32 indices): 0..18 bBucket | 19..37 bOff | 38..56 Kkey |
//   57..75 Icut | 76..94 tBelow | 95..113 tieCnt | 114..132 tieFlag
// ---------------- K2: scan histogram, find boundary buckets -------------------
__global__ void k2_scan(const u32* __restrict__ hist, u32* __restrict__ meta,
                        int nB, u32 window) {
    __shared__ u32 sp[1024];
    int t = threadIdx.x;
    const int PER = NBUCK / 1024;  // 56
    u32 s = 0;
    for (int k = 0; k < PER; k++) s += hist[t * PER + k];
    sp[t] = s; __syncthreads();
    for (int d = 1; d < 1024; d <<= 1) {
        u32 v = (t >= d) ? sp[t - d] : 0u;
        __syncthreads();
        sp[t] += v;
        __syncthreads();
    }
    u32 cum = sp[t] - s;  // exclusive prefix
    for (int k = 0; k < PER; k++) {
        u32 c = hist[t * PER + k];
        if (c) {
            for (int j = 0; j < nB; j++) {
                u32 r = (u32)(j + 1) * window;
                if (cum < r && r <= cum + c) {
                    meta[j] = (u32)(t * PER + k);   // bucket containing boundary
                    meta[NB + j] = r - cum;         // samples of this bucket below boundary
                }
            }
        }
        cum += c;
    }
}

// ---------------- K3: sub-histogram (low 10 bits) of boundary buckets ---------
__global__ __launch_bounds__(256) void k3_subhist(
        const u32* __restrict__ keys, const u32* __restrict__ meta,
        u32* __restrict__ subhist, int N, int nB) {
    __shared__ u32 sB[NB];
    if (threadIdx.x < nB) sB[threadIdx.x] = meta[threadIdx.x];
    __syncthreads();
    for (int i = blockIdx.x * blockDim.x + threadIdx.x; i < N;
         i += gridDim.x * blockDim.x) {
        u32 key = keys[i];
        u32 b = bucket_of(key);
        for (int j = 0; j < nB; j++)
            if (b == sB[j]) atomicAdd(&subhist[j * 1024 + (key & 1023u)], 1u);
    }
}

// ---------------- K4: resolve exact threshold key + tie split -----------------
__global__ void k4_resolve(const u32* __restrict__ subhist, u32* __restrict__ meta,
                           int nB) {
    int j = blockIdx.x;
    if (j >= nB) return;
    int t = threadIdx.x;  // 1024 threads
    __shared__ u32 sp[1024];
    u32 c = subhist[j * 1024 + t];
    sp[t] = c; __syncthreads();
    for (int d = 1; d < 1024; d <<= 1) {
        u32 v = (t >= d) ? sp[t - d] : 0u;
        __syncthreads();
        sp[t] += v;
        __syncthreads();
    }
    u32 incl = sp[t], excl = incl - c;
    u32 off = meta[NB + j];
    if (c && excl < off && off <= incl) {   // exactly one t matches
        meta[2 * NB + j] = KEY_MIN + (meta[j] << SUBSHIFT) + (u32)t;  // Kkey
        u32 tb = off - excl;
        meta[4 * NB + j] = tb;                                        // tBelow
        if (tb == c) { meta[3 * NB + j] = 0xFFFFFFFFu; meta[6 * NB + j] = 0u; }
        else         { meta[6 * NB + j] = 1u; }  // needs tie resolution (Icut stays 0 until k6)
    }
}

// ---------------- K5: collect indices tied at boundary keys -------------------
__global__ __launch_bounds__(256) void k5_ties(
        const u32* __restrict__ keys, const u32* __restrict__ meta,
        u32* __restrict__ tieList, int N, int nB) {
    __shared__ u32 sK[NB], sF[NB];
    if (threadIdx.x < nB) {
        sK[threadIdx.x] = meta[2 * NB + threadIdx.x];
        sF[threadIdx.x] = meta[6 * NB + threadIdx.x];
    }
    __syncthreads();
    for (int i = blockIdx.x * blockDim.x + threadIdx.x; i < N;
         i += gridDim.x * blockDim.x) {
        u32 key = keys[i];
        for (int j = 0; j < nB; j++)
            if (sF[j] && key == sK[j]) {
                u32 p = atomicAdd((u32*)&((u32*)meta)[5 * NB + j], 1u); // tieCnt
                if (p < (u32)TIECAP) tieList[j * TIECAP + p] = (u32)i;
            }
    }
}

// ---------------- K6: deterministic index cutoff among ties -------------------
__global__ void k6_cut(u32* __restrict__ tieList, u32* __restrict__ meta, int nB) {
    int j = blockIdx.x * blockDim.x + threadIdx.x;
    if (j >= nB) return;
    if (!meta[6 * NB + j]) return;
    u32 n = meta[5 * NB + j];
    if (n > (u32)TIECAP) n = TIECAP;
    u32* L = tieList + j * TIECAP;
    for (u32 a = 1; a < n; a++) {          // insertion sort (n is tiny)
        u32 v = L[a]; int b = (int)a - 1;
        while (b >= 0 && L[b] > v) { L[b + 1] = L[b]; b--; }
        L[b + 1] = v;
    }
    u32 tb = meta[4 * NB + j];
    meta[3 * NB + j] = (tb < n) ? L[tb] : 0xFFFFFFFFu;  // Icut
}

// ---------------- K7: per-bin exact accumulation ------------------------------
__global__ __launch_bounds__(256) void k7_accum(
        const u32* __restrict__ keys, const u8* __restrict__ accb,
        const u32* __restrict__ meta, u64* __restrict__ confQ,
        u32* __restrict__ accCnt, int N, int nB) {
    __shared__ unsigned long long lc[NBINS];
    __shared__ u32 la[NBINS];
    __shared__ u32 sK[NB], sI[NB];
    int t = threadIdx.x;
    if (t < NBINS) { lc[t] = 0ull; la[t] = 0u; }
    if (t < nB) { sK[t] = meta[2 * NB + t]; sI[t] = meta[3 * NB + t]; }
    __syncthreads();
    for (int i = blockIdx.x * blockDim.x + t; i < N; i += gridDim.x * blockDim.x) {
        u32 k = keys[i];
        int bin = 0;
        for (int j = 0; j < nB; j++)
            bin += (k > sK[j] || (k == sK[j] && (u32)i >= sI[j])) ? 1 : 0;
        float conf = __uint_as_float(k);
        u64 q = (u64)(conf * 4294967296.0f);  // conf * 2^32 is exact (exponent shift)
        atomicAdd(&lc[bin], (unsigned long long)q);
        atomicAdd(&la[bin], (u32)accb[i]);
    }
    __syncthreads();
    if (t < NBINS) {
        if (lc[t]) atomicAdd((unsigned long long*)&confQ[t], lc[t]);
        if (la[t]) atomicAdd(&accCnt[t], la[t]);
    }
}

// ---------------- K8: final ECE -----------------------------------------------
__global__ void k8_final(const u64* __restrict__ confQ, const u32* __restrict__ accCnt,
                         float* __restrict__ out, int window, int N) {
    if (threadIdx.x == 0 && blockIdx.x == 0) {
        double ece = 0.0;
        for (int b = 0; b < NBINS; b++) {
            double cm = (double)confQ[b] * (1.0 / 4294967296.0) / (double)window;
            double am = (double)accCnt[b] / (double)window;
            ece += fabs(cm - am);
            out[1 + b] = (float)am;
        }
        out[0] = (float)(ece * (double)window / (double)N);
    }
}

extern "C" void kernel_launch(void* const* d_in, const int* in_sizes, int n_in,
                              void* d_out, int out_size, void* d_ws, size_t ws_size,
                              hipStream_t stream) {
    const float* logits = (const float*)d_in[0];
    const int*   labels = (const int*)d_in[1];
    int N = in_sizes[1];
    int C = in_sizes[0] / N;
    float* out = (float*)d_out;

    u8* ws = (u8*)d_ws;
    // ---- workspace layout ----
    u32* keys = (u32*)ws;                                   // 4N
    u8*  accb = ws + (size_t)4 * N;                         // N
    size_t aux = ((size_t)5 * N + 255) & ~(size_t)255;
    u64* confQ   = (u64*)(ws + aux);                        // 20*8   = 160
    u32* accCnt  = (u32*)(ws + aux + 160);                  // 20*4   = 80   -> 240
    u32* hist    = (u32*)(ws + aux + 240);                  // NBUCK*4       -> 240+229376
    u32* subhist = (u32*)(ws + aux + 240 + NBUCK * 4);      // 19*1024*4 = 77824
    u32* meta    = (u32*)(ws + aux + 240 + NBUCK * 4 + NB * 1024 * 4); // 133*4
    size_t zbytes = 240 + (size_t)NBUCK * 4 + (size_t)NB * 1024 * 4 + 7 * NB * 4;
    size_t tieoff = (aux + zbytes + 255) & ~(size_t)255;
    u32* tieList = (u32*)(ws + tieoff);                     // 19*1024*4

    hipMemsetAsync(ws + aux, 0, zbytes, stream);

    int nB = NBINS - 1;
    u32 window = (u32)(N / NBINS);

    int blocks1 = (N + 255) / 256;
    k1_conf   <<<blocks1, 256, 0, stream>>>(logits, labels, keys, accb, hist, N, C);
    k2_scan   <<<1, 1024, 0, stream>>>(hist, meta, nB, window);
    k3_subhist<<<1024, 256, 0, stream>>>(keys, meta, subhist, N, nB);
    k4_resolve<<<nB, 1024, 0, stream>>>(subhist, meta, nB);
    k5_ties   <<<1024, 256, 0, stream>>>(keys, meta, tieList, N, nB);
    k6_cut    <<<1, 64, 0, stream>>>(tieList, meta, nB);
    k7_accum  <<<1024, 256, 0, stream>>>(keys, accb, meta, confQ, accCnt, N, nB);
    k8_final  <<<1, 64, 0, stream>>>(confQ, accCnt, out, (int)window, N);
}

// Round 2
// 237.336 us; speedup vs baseline: 2.1256x; 2.1256x over previous
//
#include <hip/hip_runtime.h>
#include <stdint.h>

typedef uint32_t u32;
typedef uint64_t u64;
typedef uint8_t  u8;

#define KEY_MIN   0x3C000000u   /* 0.0078125f; conf = max softmax >= 1/C = 0.01 */
#define SUBSHIFT  10
#define NBUCK     57344         /* (0x3F800000 - 0x3C000000) >> 10 */
#define NBINS     20
#define NB        19            /* NBINS - 1 boundaries */
#define TIECAP    1024

__device__ __forceinline__ u32 bucket_of(u32 key) {
    if (key < KEY_MIN) return 0u;
    u32 b = (key - KEY_MIN) >> SUBSHIFT;
    return b < (u32)NBUCK ? b : (u32)(NBUCK - 1);
}

// ---------------- K1 (C==100 specialized): 16 lanes per row, coalesced --------
// Wave = 4 groups of 16 lanes; each group owns one row. Lane sub loads float4
// #sub (256B contiguous per group) and #(sub+16) (144B tail). Shuffle-reduce
// max+argmax then sum within the 16-lane group. First-max-on-tie preserved.
__global__ __launch_bounds__(256) void k1_conf100(
        const float* __restrict__ logits, const int* __restrict__ labels,
        u32* __restrict__ keys, u8* __restrict__ accb, u32* __restrict__ hist,
        int N) {
    const int C4 = 25;                       // 100 floats = 25 float4
    int lane = threadIdx.x & 63;
    int wid  = (blockIdx.x * (blockDim.x >> 6)) + (threadIdx.x >> 6);
    int g    = lane >> 4;
    int sub  = lane & 15;
    int r    = wid * 4 + g;
    if (r >= N) return;

    const float4* row4 = (const float4*)(logits + (size_t)r * 100);
    float4 v0 = row4[sub];
    float4 v1;
    bool has2 = (sub + 16) < C4;             // sub < 9
    if (has2) v1 = row4[sub + 16];
    else      v1 = make_float4(-3.4e38f, -3.4e38f, -3.4e38f, -3.4e38f);

    // in-lane max + argmax (keep FIRST max: strict >, ascending index order)
    float m = v0.x; int am = 4 * sub;
    if (v0.y > m) { m = v0.y; am = 4 * sub + 1; }
    if (v0.z > m) { m = v0.z; am = 4 * sub + 2; }
    if (v0.w > m) { m = v0.w; am = 4 * sub + 3; }
    int b2 = 64 + 4 * sub;
    if (v1.x > m) { m = v1.x; am = b2; }
    if (v1.y > m) { m = v1.y; am = b2 + 1; }
    if (v1.z > m) { m = v1.z; am = b2 + 2; }
    if (v1.w > m) { m = v1.w; am = b2 + 3; }

    // 16-lane reduce max+argmax (xor masks stay within the group)
    #pragma unroll
    for (int off = 8; off >= 1; off >>= 1) {
        float om = __shfl_xor(m, off);
        int   oa = __shfl_xor(am, off);
        if (om > m || (om == m && oa < am)) { m = om; am = oa; }
    }

    // sum of exp(v - m)
    float s = __expf(v0.x - m) + __expf(v0.y - m) + __expf(v0.z - m) + __expf(v0.w - m);
    if (has2) s += __expf(v1.x - m) + __expf(v1.y - m) + __expf(v1.z - m) + __expf(v1.w - m);
    #pragma unroll
    for (int off = 8; off >= 1; off >>= 1) s += __shfl_xor(s, off);

    if (sub == 0) {
        float conf = 1.0f / s;               // == exp(max - logsumexp)
        u32 key = __float_as_uint(conf);
        keys[r] = key;
        accb[r] = (labels[r] == am) ? (u8)1 : (u8)0;
        atomicAdd(&hist[bucket_of(key)], 1u);
    }
}

// ---------------- K1 generic fallback (thread per row) ------------------------
__global__ __launch_bounds__(256) void k1_generic(
        const float* __restrict__ logits, const int* __restrict__ labels,
        u32* __restrict__ keys, u8* __restrict__ accb, u32* __restrict__ hist,
        int N, int C) {
    int i = blockIdx.x * blockDim.x + threadIdx.x;
    if (i >= N) return;
    const float* row = logits + (size_t)i * (size_t)C;
    float m = -3.4e38f, s = 0.f;
    int am = 0;
    for (int c = 0; c < C; c++) {
        float v = row[c];
        float nm = fmaxf(m, v); am = (v > m) ? c : am;
        s = s * __expf(m - nm) + __expf(v - nm); m = nm;
    }
    float conf = 1.0f / s;
    u32 key = __float_as_uint(conf);
    keys[i] = key;
    accb[i] = (labels[i] == am) ? (u8)1 : (u8)0;
    atomicAdd(&hist[bucket_of(key)], 1u);
}

// meta layout (u32 indices): 0..18 bBucket | 19..37 bOff | 38..56 Kkey |
//   57..75 Icut | 76..94 tBelow | 95..113 tieCnt | 114..132 tieFlag
// ---------------- K2: scan histogram, find boundary buckets -------------------
__global__ void k2_scan(const u32* __restrict__ hist, u32* __restrict__ meta,
                        int nB, u32 window) {
    __shared__ u32 sp[1024];
    int t = threadIdx.x;
    const int PER = NBUCK / 1024;  // 56
    u32 s = 0;
    for (int k = 0; k < PER; k++) s += hist[t * PER + k];
    sp[t] = s; __syncthreads();
    for (int d = 1; d < 1024; d <<= 1) {
        u32 v = (t >= d) ? sp[t - d] : 0u;
        __syncthreads();
        sp[t] += v;
        __syncthreads();
    }
    u32 cum = sp[t] - s;  // exclusive prefix
    for (int k = 0; k < PER; k++) {
        u32 c = hist[t * PER + k];
        if (c) {
            for (int j = 0; j < nB; j++) {
                u32 r = (u32)(j + 1) * window;
                if (cum < r && r <= cum + c) {
                    meta[j] = (u32)(t * PER + k);   // bucket containing boundary
                    meta[NB + j] = r - cum;         // samples of this bucket below boundary
                }
            }
        }
        cum += c;
    }
}

// ---------------- K3: sub-histogram (low 10 bits) of boundary buckets ---------
__global__ __launch_bounds__(256) void k3_subhist(
        const u32* __restrict__ keys, const u32* __restrict__ meta,
        u32* __restrict__ subhist, int N, int nB) {
    __shared__ u32 sB[NB];
    if (threadIdx.x < nB) sB[threadIdx.x] = meta[threadIdx.x];
    __syncthreads();
    for (int i = blockIdx.x * blockDim.x + threadIdx.x; i < N;
         i += gridDim.x * blockDim.x) {
        u32 key = keys[i];
        u32 b = bucket_of(key);
        for (int j = 0; j < nB; j++)
            if (b == sB[j]) atomicAdd(&subhist[j * 1024 + (key & 1023u)], 1u);
    }
}

// ---------------- K4: resolve exact threshold key + tie split -----------------
__global__ void k4_resolve(const u32* __restrict__ subhist, u32* __restrict__ meta,
                           int nB) {
    int j = blockIdx.x;
    if (j >= nB) return;
    int t = threadIdx.x;  // 1024 threads
    __shared__ u32 sp[1024];
    u32 c = subhist[j * 1024 + t];
    sp[t] = c; __syncthreads();
    for (int d = 1; d < 1024; d <<= 1) {
        u32 v = (t >= d) ? sp[t - d] : 0u;
        __syncthreads();
        sp[t] += v;
        __syncthreads();
    }
    u32 incl = sp[t], excl = incl - c;
    u32 off = meta[NB + j];
    if (c && excl < off && off <= incl) {   // exactly one t matches
        meta[2 * NB + j] = KEY_MIN + (meta[j] << SUBSHIFT) + (u32)t;  // Kkey
        u32 tb = off - excl;
        meta[4 * NB + j] = tb;                                        // tBelow
        if (tb == c) { meta[3 * NB + j] = 0xFFFFFFFFu; meta[6 * NB + j] = 0u; }
        else         { meta[6 * NB + j] = 1u; }  // needs tie resolution
    }
}

// ---------------- K5: collect indices tied at boundary keys -------------------
__global__ __launch_bounds__(256) void k5_ties(
        const u32* __restrict__ keys, const u32* __restrict__ meta,
        u32* __restrict__ tieList, int N, int nB) {
    __shared__ u32 sK[NB], sF[NB];
    if (threadIdx.x < nB) {
        sK[threadIdx.x] = meta[2 * NB + threadIdx.x];
        sF[threadIdx.x] = meta[6 * NB + threadIdx.x];
    }
    __syncthreads();
    for (int i = blockIdx.x * blockDim.x + threadIdx.x; i < N;
         i += gridDim.x * blockDim.x) {
        u32 key = keys[i];
        for (int j = 0; j < nB; j++)
            if (sF[j] && key == sK[j]) {
                u32 p = atomicAdd((u32*)&((u32*)meta)[5 * NB + j], 1u); // tieCnt
                if (p < (u32)TIECAP) tieList[j * TIECAP + p] = (u32)i;
            }
    }
}

// ---------------- K6: deterministic index cutoff among ties -------------------
__global__ void k6_cut(u32* __restrict__ tieList, u32* __restrict__ meta, int nB) {
    int j = blockIdx.x * blockDim.x + threadIdx.x;
    if (j >= nB) return;
    if (!meta[6 * NB + j]) return;
    u32 n = meta[5 * NB + j];
    if (n > (u32)TIECAP) n = TIECAP;
    u32* L = tieList + j * TIECAP;
    for (u32 a = 1; a < n; a++) {          // insertion sort (n is tiny)
        u32 v = L[a]; int b = (int)a - 1;
        while (b >= 0 && L[b] > v) { L[b + 1] = L[b]; b--; }
        L[b + 1] = v;
    }
    u32 tb = meta[4 * NB + j];
    meta[3 * NB + j] = (tb < n) ? L[tb] : 0xFFFFFFFFu;  // Icut
}

// ---------------- K7: per-bin exact accumulation (per-wave LDS bins) ----------
__global__ __launch_bounds__(256) void k7_accum(
        const u32* __restrict__ keys, const u8* __restrict__ accb,
        const u32* __restrict__ meta, u64* __restrict__ confQ,
        u32* __restrict__ accCnt, int N, int nB) {
    __shared__ unsigned long long lc[4][NBINS];
    __shared__ u32 la[4][NBINS];
    __shared__ u32 sK[NB], sI[NB];
    int t = threadIdx.x;
    int w = t >> 6;
    if (t < 4 * NBINS) { lc[t / NBINS][t % NBINS] = 0ull; la[t / NBINS][t % NBINS] = 0u; }
    if (t < nB) { sK[t] = meta[2 * NB + t]; sI[t] = meta[3 * NB + t]; }
    __syncthreads();
    for (int i = blockIdx.x * blockDim.x + t; i < N; i += gridDim.x * blockDim.x) {
        u32 k = keys[i];
        int bin = 0;
        #pragma unroll
        for (int j = 0; j < NB; j++)
            bin += (k > sK[j] || (k == sK[j] && (u32)i >= sI[j])) ? 1 : 0;
        float conf = __uint_as_float(k);
        u64 q = (u64)(conf * 4294967296.0f);  // conf * 2^32 exact (exponent shift)
        atomicAdd(&lc[w][bin], (unsigned long long)q);
        atomicAdd(&la[w][bin], (u32)accb[i]);
    }
    __syncthreads();
    if (t < NBINS) {
        unsigned long long cq = lc[0][t] + lc[1][t] + lc[2][t] + lc[3][t];
        u32 ac = la[0][t] + la[1][t] + la[2][t] + la[3][t];
        if (cq) atomicAdd((unsigned long long*)&confQ[t], cq);
        if (ac) atomicAdd(&accCnt[t], ac);
    }
}

// ---------------- K8: final ECE -----------------------------------------------
__global__ void k8_final(const u64* __restrict__ confQ, const u32* __restrict__ accCnt,
                         float* __restrict__ out, int window, int N) {
    if (threadIdx.x == 0 && blockIdx.x == 0) {
        double ece = 0.0;
        for (int b = 0; b < NBINS; b++) {
            double cm = (double)confQ[b] * (1.0 / 4294967296.0) / (double)window;
            double am = (double)accCnt[b] / (double)window;
            ece += fabs(cm - am);
            out[1 + b] = (float)am;
        }
        out[0] = (float)(ece * (double)window / (double)N);
    }
}

extern "C" void kernel_launch(void* const* d_in, const int* in_sizes, int n_in,
                              void* d_out, int out_size, void* d_ws, size_t ws_size,
                              hipStream_t stream) {
    const float* logits = (const float*)d_in[0];
    const int*   labels = (const int*)d_in[1];
    int N = in_sizes[1];
    int C = in_sizes[0] / N;
    float* out = (float*)d_out;

    u8* ws = (u8*)d_ws;
    // ---- workspace layout ----
    u32* keys = (u32*)ws;                                   // 4N
    u8*  accb = ws + (size_t)4 * N;                         // N
    size_t aux = ((size_t)5 * N + 255) & ~(size_t)255;
    u64* confQ   = (u64*)(ws + aux);                        // 20*8   = 160
    u32* accCnt  = (u32*)(ws + aux + 160);                  // 20*4   = 80   -> 240
    u32* hist    = (u32*)(ws + aux + 240);                  // NBUCK*4
    u32* subhist = (u32*)(ws + aux + 240 + NBUCK * 4);      // 19*1024*4
    u32* meta    = (u32*)(ws + aux + 240 + NBUCK * 4 + NB * 1024 * 4); // 133*4
    size_t zbytes = 240 + (size_t)NBUCK * 4 + (size_t)NB * 1024 * 4 + 7 * NB * 4;
    size_t tieoff = (aux + zbytes + 255) & ~(size_t)255;
    u32* tieList = (u32*)(ws + tieoff);                     // 19*1024*4

    hipMemsetAsync(ws + aux, 0, zbytes, stream);

    int nB = NBINS - 1;
    u32 window = (u32)(N / NBINS);

    if (C == 100) {
        int rows_per_block = 16;  // 4 waves x 4 groups
        int blocks1 = (N + rows_per_block - 1) / rows_per_block;
        k1_conf100<<<blocks1, 256, 0, stream>>>(logits, labels, keys, accb, hist, N);
    } else {
        int blocks1 = (N + 255) / 256;
        k1_generic<<<blocks1, 256, 0, stream>>>(logits, labels, keys, accb, hist, N, C);
    }
    k2_scan   <<<1, 1024, 0, stream>>>(hist, meta, nB, window);
    k3_subhist<<<1024, 256, 0, stream>>>(keys, meta, subhist, N, nB);
    k4_resolve<<<nB, 1024, 0, stream>>>(subhist, meta, nB);
    k5_ties   <<<1024, 256, 0, stream>>>(keys, meta, tieList, N, nB);
    k6_cut    <<<1, 64, 0, stream>>>(tieList, meta, nB);
    k7_accum  <<<1024, 256, 0, stream>>>(keys, accb, meta, confQ, accCnt, N, nB);
    k8_final  <<<1, 64, 0, stream>>>(confQ, accCnt, out, (int)window, N);
}